// Round 3
// baseline (909.434 us; speedup 1.0000x reference)
//
#include <hip/hip_runtime.h>
#include <hip/hip_bf16.h>
#include <stdint.h>

typedef __attribute__((ext_vector_type(16))) float f32x16;
typedef __attribute__((ext_vector_type(8))) int i32x8;

#define M_DIM 8192
#define N_DIM 4096
#define K_DIM 4096
#define NX_INV (1.0f / 33554432.0f)
#define NW_INV (1.0f / 16777216.0f)

#define AS3(p) ((__attribute__((address_space(3))) uint32_t*)(uint32_t)(uintptr_t)(p))
#define AS1(p) ((const __attribute__((address_space(1))) uint32_t*)(uintptr_t)(p))

// ---------------- sum(|x|) reduction, fp64 atomic accumulation ----------------
__global__ void absum_kernel(const float* __restrict__ x, int n4, double* __restrict__ out) {
    int i = blockIdx.x * blockDim.x + threadIdx.x;
    int stride = gridDim.x * blockDim.x;
    const float4* x4 = (const float4*)x;
    float s = 0.f;
    for (; i < n4; i += stride) {
        float4 v = x4[i];
        s += fabsf(v.x) + fabsf(v.y) + fabsf(v.z) + fabsf(v.w);
    }
    #pragma unroll
    for (int off = 32; off >= 1; off >>= 1) s += __shfl_down(s, off, 64);
    __shared__ float wsum[4];
    int lane = threadIdx.x & 63, wid = threadIdx.x >> 6;
    if (lane == 0) wsum[wid] = s;
    __syncthreads();
    if (threadIdx.x == 0) {
        double tot = (double)wsum[0] + (double)wsum[1] + (double)wsum[2] + (double)wsum[3];
        atomicAdd(out, tot);
    }
}

// ---------------- fp4 e2m1 nibble: searchsorted index IS the e2m1 magnitude code ----
__device__ __forceinline__ uint32_t enc_nib(float y) {
    float a = fabsf(y);
    uint32_t idx;
    if (a < 1.75f) idx = (a < 0.75f) ? ((a < 0.25f) ? 0u : 1u) : ((a < 1.25f) ? 2u : 3u);
    else           idx = (a < 3.5f)  ? ((a < 2.5f)  ? 4u : 5u) : ((a < 5.0f)  ? 6u : 7u);
    return idx | ((__float_as_uint(y) >> 31) << 3);
}

// quant + pack fragment-major:
//   unit (mb, kt, l) = 16 B: rows mb*32+(l&31), k in [kt*64+(l>>5)*32, +32), 2 nibbles/byte
//   P dword offset = ((mb*64 + kt)*64 + l)*4
__global__ void quant_pack_kernel(const float* __restrict__ X, uint32_t* __restrict__ P,
                                  int mb_count, const double* __restrict__ sum, float invN) {
    float s = (float)(*sum) * invN;
    int gw = blockIdx.x * (blockDim.x >> 6) + (threadIdx.x >> 6);
    int l = threadIdx.x & 63;
    int mb = gw >> 6;
    int kt = gw & 63;
    if (mb >= mb_count) return;
    const float* src = X + (size_t)(mb * 32 + (l & 31)) * K_DIM + kt * 64 + (l >> 5) * 32;
    uint32_t o[4];
    #pragma unroll
    for (int d = 0; d < 4; d++) {
        const float* p8 = src + d * 8;
        uint32_t w = 0;
        #pragma unroll
        for (int j = 0; j < 8; j++) w |= enc_nib(p8[j] / s) << (4 * j);
        o[d] = w;
    }
    *(uint4*)(P + ((size_t)(mb * 64 + kt) * 64 + l) * 4) = make_uint4(o[0], o[1], o[2], o[3]);
}

// ---------------- fp4 MX GEMM: C = (A·B^T)*scale + bias ----------------
// 256x256 tile, K-step 64, 8 waves (2Mx4N, wave=128x64), 4-deep LDS ring (64 KB),
// counted vmcnt, setprio. mfma_scale_f32_32x32x64_f8f6f4 (fmt 4 = fp4), unit scales.
#define NKT 64
#define NWG 512

__device__ __forceinline__ void glds16(const uint32_t* g, uint32_t* l) {
    __builtin_amdgcn_global_load_lds(AS1(g), AS3(l), 16, 0, 0);
}

__global__ __launch_bounds__(512, 2)
void gemm_kernel(const uint32_t* __restrict__ Ap, const uint32_t* __restrict__ Bp,
                 const float* __restrict__ bias, float* __restrict__ C,
                 const double* __restrict__ sums) {
    // 4 ring slots x (A 8KB + B 8KB) = 64 KB
    __shared__ uint32_t lds[4 * 4096];

    int bid = blockIdx.x;
    int swz = (bid & 7) * (NWG >> 3) + (bid >> 3);  // 512 % 8 == 0 -> bijective
    int bn = (swz & 15) * 256;
    int bm = (swz >> 4) * 256;

    int t = threadIdx.x;
    int lane = t & 63;
    int wm = (t >> 6) >> 2;          // 0..1
    int wn = (t >> 6) & 3;           // 0..3

    // staging: thread t loads unit (mb-sub = t>>6, lane index t&63); 1 A + 1 B load/tile
    const uint32_t* gA = Ap + (size_t)((bm >> 5) + (t >> 6)) * 16384 + (t & 63) * 4;
    const uint32_t* gB = Bp + (size_t)((bn >> 5) + (t >> 6)) * 16384 + (t & 63) * 4;
    uint32_t* ldA = lds + t * 4;           // slot-local A: [0, 2048) dwords
    uint32_t* ldB = lds + 2048 + t * 4;    // slot-local B: [2048, 4096)

    // fragment read offsets (lane-linear 16B -> conflict-free by construction)
    int offA[4], offB[2];
    #pragma unroll
    for (int m = 0; m < 4; m++) offA[m] = ((wm * 4 + m) * 64 + lane) * 4;
    #pragma unroll
    for (int n = 0; n < 2; n++) offB[n] = 2048 + ((wn * 2 + n) * 64 + lane) * 4;

    f32x16 acc[4][2];
    #pragma unroll
    for (int m = 0; m < 4; m++)
        #pragma unroll
        for (int n = 0; n < 2; n++) acc[m][n] = (f32x16)0.f;

    #pragma unroll
    for (int pt = 0; pt < 3; pt++) {       // stage tiles 0,1,2
        glds16(gA + pt * 256, ldA + pt * 4096);
        glds16(gB + pt * 256, ldB + pt * 4096);
    }

    for (int kt = 0; kt < NKT; kt++) {
        // tile kt landed; tiles kt+1, kt+2 (2 loads each) may stay in flight
        if (kt <= NKT - 3)      asm volatile("s_waitcnt vmcnt(4)" ::: "memory");
        else if (kt == NKT - 2) asm volatile("s_waitcnt vmcnt(2)" ::: "memory");
        else                    asm volatile("s_waitcnt vmcnt(0)" ::: "memory");
        asm volatile("s_barrier" ::: "memory");   // also seals prev iter's reads (WAR)

        const uint32_t* rb = lds + (kt & 3) * 4096;
        if (kt + 3 < NKT) {
            int so = ((kt + 3) & 3) * 4096;
            glds16(gA + (kt + 3) * 256, ldA + so);
            glds16(gB + (kt + 3) * 256, ldB + so);
        }

        i32x8 va[4], vb[2];
        #pragma unroll
        for (int m = 0; m < 4; m++) {
            uint4 u = *(const uint4*)&rb[offA[m]];
            va[m][0] = u.x; va[m][1] = u.y; va[m][2] = u.z; va[m][3] = u.w;
            va[m][4] = u.x; va[m][5] = u.y; va[m][6] = u.z; va[m][7] = u.w;  // dup: fp4 uses 4 regs
        }
        #pragma unroll
        for (int n = 0; n < 2; n++) {
            uint4 u = *(const uint4*)&rb[offB[n]];
            vb[n][0] = u.x; vb[n][1] = u.y; vb[n][2] = u.z; vb[n][3] = u.w;
            vb[n][4] = u.x; vb[n][5] = u.y; vb[n][6] = u.z; vb[n][7] = u.w;
        }

        __builtin_amdgcn_s_setprio(1);
        #pragma unroll
        for (int m = 0; m < 4; m++)
            #pragma unroll
            for (int n = 0; n < 2; n++)
                acc[m][n] = __builtin_amdgcn_mfma_scale_f32_32x32x64_f8f6f4(
                    va[m], vb[n], acc[m][n],
                    4, 4,                     // cbsz/blgp: fmt 4 = fp4 e2m1
                    0, 0x7F7F7F7F,            // opsel_a, scale_a = e8m0 1.0 everywhere
                    0, 0x7F7F7F7F);           // opsel_b, scale_b
        __builtin_amdgcn_s_setprio(0);
    }

    float scale = (float)((sums[0] * (1.0 / 33554432.0)) * (sums[1] * (1.0 / 16777216.0)));

    // C/D 32x32 layout (verified, dtype-independent): col=lane&31, row=(i&3)+8*(i>>2)+4*(lane>>5)
    int colb = bn + wn * 64 + (lane & 31);
    int rowb = bm + wm * 128 + ((lane >> 5) << 2);
    #pragma unroll
    for (int m = 0; m < 4; m++)
        #pragma unroll
        for (int n = 0; n < 2; n++) {
            int col = colb + n * 32;
            float bv = bias[col];
            #pragma unroll
            for (int i = 0; i < 16; i++) {
                int row = rowb + m * 32 + (i & 3) + ((i >> 2) << 3);
                C[(size_t)row * N_DIM + col] = acc[m][n][i] * scale + bv;
            }
        }
}

extern "C" void kernel_launch(void* const* d_in, const int* in_sizes, int n_in,
                              void* d_out, int out_size, void* d_ws, size_t ws_size,
                              hipStream_t stream) {
    const float* x    = (const float*)d_in[0];   // [4,2048,4096]
    const float* w    = (const float*)d_in[1];   // [4096,4096]
    const float* bias = (const float*)d_in[2];   // [4096]
    float* out = (float*)d_out;                  // [4,2048,4096] fp32

    double* sums = (double*)d_ws;
    uint32_t* Xp = (uint32_t*)((char*)d_ws + 1024);   // 16 MB packed fp4, fragment-major
    uint32_t* Wp = Xp + (size_t)256 * 64 * 64 * 4;    // 8 MB

    hipMemsetAsync(d_ws, 0, 1024, stream);
    absum_kernel<<<2048, 256, 0, stream>>>(x, 33554432 / 4, sums + 0);
    absum_kernel<<<2048, 256, 0, stream>>>(w, 16777216 / 4, sums + 1);
    // X: 256 mb-blocks x 64 kt = 16384 waves; W: 128 x 64 = 8192 waves (4 waves/block)
    quant_pack_kernel<<<4096, 256, 0, stream>>>(x, Xp, 256, sums + 0, NX_INV);
    quant_pack_kernel<<<2048, 256, 0, stream>>>(w, Wp, 128, sums + 1, NW_INV);
    gemm_kernel<<<NWG, 512, 0, stream>>>(Xp, Wp, bias, out, sums);
}

// Round 4
// 236.015 us; speedup vs baseline: 3.8533x; 3.8533x over previous
//
#include <hip/hip_runtime.h>
#include <hip/hip_bf16.h>
#include <stdint.h>

typedef __attribute__((ext_vector_type(16))) float f32x16;
typedef __attribute__((ext_vector_type(8))) int i32x8;

#define M_DIM 8192
#define N_DIM 4096
#define K_DIM 4096
#define NX_INV (1.0f / 33554432.0f)
#define NW_INV (1.0f / 16777216.0f)

#define AS3(p) ((__attribute__((address_space(3))) uint32_t*)(uint32_t)(uintptr_t)(p))
#define AS1(p) ((const __attribute__((address_space(1))) uint32_t*)(uintptr_t)(p))

// ---------------- sum(|x|) reduction, fp64 atomic accumulation ----------------
__global__ void absum_kernel(const float* __restrict__ x, int n4, double* __restrict__ out) {
    int i = blockIdx.x * blockDim.x + threadIdx.x;
    int stride = gridDim.x * blockDim.x;
    const float4* x4 = (const float4*)x;
    float s = 0.f;
    for (; i < n4; i += stride) {
        float4 v = x4[i];
        s += fabsf(v.x) + fabsf(v.y) + fabsf(v.z) + fabsf(v.w);
    }
    #pragma unroll
    for (int off = 32; off >= 1; off >>= 1) s += __shfl_down(s, off, 64);
    __shared__ float wsum[4];
    int lane = threadIdx.x & 63, wid = threadIdx.x >> 6;
    if (lane == 0) wsum[wid] = s;
    __syncthreads();
    if (threadIdx.x == 0) {
        double tot = (double)wsum[0] + (double)wsum[1] + (double)wsum[2] + (double)wsum[3];
        atomicAdd(out, tot);
    }
}

// ---------------- fp4 e2m1 encode via pre-scaled thresholds ----------------
// reference: idx = searchsorted(mids, |x/s|, 'right'); here: idx = #{ s*mid_j <= |x| }
__device__ __forceinline__ uint32_t enc_nib_t(float x, float t0, float t1, float t2,
                                              float t3, float t4, float t5, float t6) {
    float a = fabsf(x);
    uint32_t idx;
    if (a < t3) idx = (a < t1) ? ((a < t0) ? 0u : 1u) : ((a < t2) ? 2u : 3u);
    else        idx = (a < t5) ? ((a < t4) ? 4u : 5u) : ((a < t6) ? 6u : 7u);
    return idx | ((__float_as_uint(x) >> 31) << 3);
}

// quant + pack fragment-major (LDS-staged transpose, coalesced global R/W):
//   unit (mb, kt, l) = 16 B: row mb*32+(l&31), k in [kt*64+(l>>5)*32, +32), 2 nibbles/byte
//   P dword offset = ((mb*64 + kt)*64 + l)*4
// block: 256 thr handles (mb, ktg): 32 rows x 256 cols; grid = mb_count*16
__global__ void quant_pack_kernel(const float* __restrict__ X, uint32_t* __restrict__ P,
                                  const double* __restrict__ sum, float invN) {
    __shared__ float4 tile[32 * 64];   // 32 KB, unit-swizzled: [row*64 + (col4 ^ (row&7))]

    float s = (float)(*sum) * invN;
    float t0 = 0.25f * s, t1 = 0.75f * s, t2 = 1.25f * s, t3 = 1.75f * s;
    float t4 = 2.5f * s,  t5 = 3.5f * s,  t6 = 5.0f * s;

    int mb  = blockIdx.x >> 4;
    int ktg = blockIdx.x & 15;
    int t = threadIdx.x;

    // ---- coalesced load: 8 passes x (4 rows x 64 float4) ----
    {
        int row0 = t >> 6;            // 0..3
        int col4 = t & 63;
        const float4* src = (const float4*)(X + (size_t)(mb * 32 + row0) * K_DIM + ktg * 256) + col4;
        #pragma unroll
        for (int p = 0; p < 8; p++) {
            int row = p * 4 + row0;
            tile[row * 64 + (col4 ^ (row & 7))] = src[(size_t)p * 4 * (K_DIM / 4)];
        }
    }
    __syncthreads();

    // ---- encode: warp w -> kt_local = w; lane gathers 32 consecutive floats from LDS ----
    int w = t >> 6;                   // kt_local 0..3
    int l = t & 63;
    int row = l & 31;
    int ub = w * 16 + (l >> 5) * 8;   // first unit (float4) index within row
    uint32_t o[4];
    #pragma unroll
    for (int d = 0; d < 4; d++) {
        float4 f0 = tile[row * 64 + ((ub + 2 * d)     ^ (row & 7))];
        float4 f1 = tile[row * 64 + ((ub + 2 * d + 1) ^ (row & 7))];
        o[d] =  enc_nib_t(f0.x, t0,t1,t2,t3,t4,t5,t6)
             | (enc_nib_t(f0.y, t0,t1,t2,t3,t4,t5,t6) << 4)
             | (enc_nib_t(f0.z, t0,t1,t2,t3,t4,t5,t6) << 8)
             | (enc_nib_t(f0.w, t0,t1,t2,t3,t4,t5,t6) << 12)
             | (enc_nib_t(f1.x, t0,t1,t2,t3,t4,t5,t6) << 16)
             | (enc_nib_t(f1.y, t0,t1,t2,t3,t4,t5,t6) << 20)
             | (enc_nib_t(f1.z, t0,t1,t2,t3,t4,t5,t6) << 24)
             | (enc_nib_t(f1.w, t0,t1,t2,t3,t4,t5,t6) << 28);
    }
    int kt = ktg * 4 + w;
    *(uint4*)(P + ((size_t)(mb * 64 + kt) * 64 + l) * 4) = make_uint4(o[0], o[1], o[2], o[3]);
}

// ---------------- fp4 MX GEMM: C = (A·B^T)*scale + bias ----------------
// 256x256 tile, K-step 64, 8 waves (2Mx4N, wave=128x64), 4-deep LDS ring (64 KB),
// counted vmcnt, setprio. mfma_scale_f32_32x32x64_f8f6f4 (fmt 4 = fp4), unit scales.
#define NKT 64
#define NWG 512

__device__ __forceinline__ void glds16(const uint32_t* g, uint32_t* l) {
    __builtin_amdgcn_global_load_lds(AS1(g), AS3(l), 16, 0, 0);
}

__global__ __launch_bounds__(512, 2)
void gemm_kernel(const uint32_t* __restrict__ Ap, const uint32_t* __restrict__ Bp,
                 const float* __restrict__ bias, float* __restrict__ C,
                 const double* __restrict__ sums) {
    // 4 ring slots x (A 8KB + B 8KB) = 64 KB
    __shared__ uint32_t lds[4 * 4096];

    int bid = blockIdx.x;
    int swz = (bid & 7) * (NWG >> 3) + (bid >> 3);  // 512 % 8 == 0 -> bijective
    int bn = (swz & 15) * 256;
    int bm = (swz >> 4) * 256;

    int t = threadIdx.x;
    int lane = t & 63;
    int wm = (t >> 6) >> 2;          // 0..1
    int wn = (t >> 6) & 3;           // 0..3

    const uint32_t* gA = Ap + (size_t)((bm >> 5) + (t >> 6)) * 16384 + (t & 63) * 4;
    const uint32_t* gB = Bp + (size_t)((bn >> 5) + (t >> 6)) * 16384 + (t & 63) * 4;
    uint32_t* ldA = lds + t * 4;
    uint32_t* ldB = lds + 2048 + t * 4;

    int offA[4], offB[2];
    #pragma unroll
    for (int m = 0; m < 4; m++) offA[m] = ((wm * 4 + m) * 64 + lane) * 4;
    #pragma unroll
    for (int n = 0; n < 2; n++) offB[n] = 2048 + ((wn * 2 + n) * 64 + lane) * 4;

    f32x16 acc[4][2];
    #pragma unroll
    for (int m = 0; m < 4; m++)
        #pragma unroll
        for (int n = 0; n < 2; n++) acc[m][n] = (f32x16)0.f;

    #pragma unroll
    for (int pt = 0; pt < 3; pt++) {
        glds16(gA + pt * 256, ldA + pt * 4096);
        glds16(gB + pt * 256, ldB + pt * 4096);
    }

    for (int kt = 0; kt < NKT; kt++) {
        if (kt <= NKT - 3)      asm volatile("s_waitcnt vmcnt(4)" ::: "memory");
        else if (kt == NKT - 2) asm volatile("s_waitcnt vmcnt(2)" ::: "memory");
        else                    asm volatile("s_waitcnt vmcnt(0)" ::: "memory");
        asm volatile("s_barrier" ::: "memory");

        const uint32_t* rb = lds + (kt & 3) * 4096;
        if (kt + 3 < NKT) {
            int so = ((kt + 3) & 3) * 4096;
            glds16(gA + (kt + 3) * 256, ldA + so);
            glds16(gB + (kt + 3) * 256, ldB + so);
        }

        i32x8 va[4], vb[2];
        #pragma unroll
        for (int m = 0; m < 4; m++) {
            uint4 u = *(const uint4*)&rb[offA[m]];
            va[m][0] = u.x; va[m][1] = u.y; va[m][2] = u.z; va[m][3] = u.w;
            va[m][4] = u.x; va[m][5] = u.y; va[m][6] = u.z; va[m][7] = u.w;
        }
        #pragma unroll
        for (int n = 0; n < 2; n++) {
            uint4 u = *(const uint4*)&rb[offB[n]];
            vb[n][0] = u.x; vb[n][1] = u.y; vb[n][2] = u.z; vb[n][3] = u.w;
            vb[n][4] = u.x; vb[n][5] = u.y; vb[n][6] = u.z; vb[n][7] = u.w;
        }

        __builtin_amdgcn_s_setprio(1);
        #pragma unroll
        for (int m = 0; m < 4; m++)
            #pragma unroll
            for (int n = 0; n < 2; n++)
                acc[m][n] = __builtin_amdgcn_mfma_scale_f32_32x32x64_f8f6f4(
                    va[m], vb[n], acc[m][n],
                    4, 4, 0, 0x7F7F7F7F, 0, 0x7F7F7F7F);
        __builtin_amdgcn_s_setprio(0);
    }

    float scale = (float)((sums[0] * (1.0 / 33554432.0)) * (sums[1] * (1.0 / 16777216.0)));

    int colb = bn + wn * 64 + (lane & 31);
    int rowb = bm + wm * 128 + ((lane >> 5) << 2);
    #pragma unroll
    for (int m = 0; m < 4; m++)
        #pragma unroll
        for (int n = 0; n < 2; n++) {
            int col = colb + n * 32;
            float bv = bias[col];
            #pragma unroll
            for (int i = 0; i < 16; i++) {
                int row = rowb + m * 32 + (i & 3) + ((i >> 2) << 3);
                C[(size_t)row * N_DIM + col] = acc[m][n][i] * scale + bv;
            }
        }
}

extern "C" void kernel_launch(void* const* d_in, const int* in_sizes, int n_in,
                              void* d_out, int out_size, void* d_ws, size_t ws_size,
                              hipStream_t stream) {
    const float* x    = (const float*)d_in[0];   // [4,2048,4096]
    const float* w    = (const float*)d_in[1];   // [4096,4096]
    const float* bias = (const float*)d_in[2];   // [4096]
    float* out = (float*)d_out;                  // [4,2048,4096] fp32

    double* sums = (double*)d_ws;
    uint32_t* Xp = (uint32_t*)((char*)d_ws + 1024);   // 16 MB packed fp4, fragment-major
    uint32_t* Wp = Xp + (size_t)256 * 64 * 64 * 4;    // 8 MB

    hipMemsetAsync(d_ws, 0, 1024, stream);
    absum_kernel<<<2048, 256, 0, stream>>>(x, 33554432 / 4, sums + 0);
    absum_kernel<<<2048, 256, 0, stream>>>(w, 16777216 / 4, sums + 1);
    quant_pack_kernel<<<4096, 256, 0, stream>>>(x, Xp, sums + 0, NX_INV);
    quant_pack_kernel<<<2048, 256, 0, stream>>>(w, Wp, sums + 1, NW_INV);
    gemm_kernel<<<NWG, 512, 0, stream>>>(Xp, Wp, bias, out, sums);
}

// Round 5
// 186.114 us; speedup vs baseline: 4.8864x; 1.2681x over previous
//
#include <hip/hip_runtime.h>
#include <hip/hip_bf16.h>
#include <stdint.h>

typedef __attribute__((ext_vector_type(16))) float f32x16;
typedef __attribute__((ext_vector_type(8))) int i32x8;

#define M_DIM 8192
#define N_DIM 4096
#define K_DIM 4096
#define NX_INV (1.0f / 33554432.0f)
#define NW_INV (1.0f / 16777216.0f)

#define AS3(p) ((__attribute__((address_space(3))) uint32_t*)(uint32_t)(uintptr_t)(p))
#define AS1(p) ((const __attribute__((address_space(1))) uint32_t*)(uintptr_t)(p))

// ---------------- fused |x|,|w| sum reduction (one launch), fp64 atomics ----------------
__global__ void absum2_kernel(const float* __restrict__ x, const float* __restrict__ w,
                              double* __restrict__ sums) {
    bool isw = blockIdx.x >= 2048;
    const float4* src = (const float4*)(isw ? w : x);
    int n4  = isw ? (16777216 / 4) : (33554432 / 4);
    int bid = isw ? (blockIdx.x - 2048) : blockIdx.x;
    int nb  = isw ? 1024 : 2048;
    int i = bid * blockDim.x + threadIdx.x;
    int stride = nb * blockDim.x;
    float s = 0.f;
    for (; i < n4; i += stride) {
        float4 v = src[i];
        s += fabsf(v.x) + fabsf(v.y) + fabsf(v.z) + fabsf(v.w);
    }
    #pragma unroll
    for (int off = 32; off >= 1; off >>= 1) s += __shfl_down(s, off, 64);
    __shared__ float wsum[4];
    int lane = threadIdx.x & 63, wid = threadIdx.x >> 6;
    if (lane == 0) wsum[wid] = s;
    __syncthreads();
    if (threadIdx.x == 0) {
        double tot = (double)wsum[0] + (double)wsum[1] + (double)wsum[2] + (double)wsum[3];
        atomicAdd(&sums[isw ? 1 : 0], tot);
    }
}

// ---------------- fp4 e2m1 encode via pre-scaled thresholds ----------------
__device__ __forceinline__ uint32_t enc_nib_t(float x, float t0, float t1, float t2,
                                              float t3, float t4, float t5, float t6) {
    float a = fabsf(x);
    uint32_t idx;
    if (a < t3) idx = (a < t1) ? ((a < t0) ? 0u : 1u) : ((a < t2) ? 2u : 3u);
    else        idx = (a < t5) ? ((a < t4) ? 4u : 5u) : ((a < t6) ? 6u : 7u);
    return idx | ((__float_as_uint(x) >> 31) << 3);
}

// fused quant+pack for X and W (one launch); fragment-major output:
//   unit (mb, kt, l) = 16 B: row mb*32+(l&31), k in [kt*64+(l>>5)*32, +32)
//   P dword offset = ((mb*64 + kt)*64 + l)*4
__global__ void quant2_kernel(const float* __restrict__ X, const float* __restrict__ W,
                              uint32_t* __restrict__ Xp, uint32_t* __restrict__ Wp,
                              const double* __restrict__ sums) {
    __shared__ float4 tile[32 * 64];   // 32 KB, unit-swizzled: [row*64 + (col4 ^ (row&7))]

    bool isw = blockIdx.x >= 4096;
    const float* src_base = isw ? W : X;
    uint32_t* dst = isw ? Wp : Xp;
    float s = (float)(sums[isw ? 1 : 0]) * (isw ? NW_INV : NX_INV);
    int bid = isw ? (blockIdx.x - 4096) : blockIdx.x;

    float t0 = 0.25f * s, t1 = 0.75f * s, t2 = 1.25f * s, t3 = 1.75f * s;
    float t4 = 2.5f * s,  t5 = 3.5f * s,  t6 = 5.0f * s;

    int mb  = bid >> 4;
    int ktg = bid & 15;
    int t = threadIdx.x;

    // ---- coalesced load: 8 passes x (4 rows x 64 float4) ----
    {
        int row0 = t >> 6;            // 0..3
        int col4 = t & 63;
        const float4* src = (const float4*)(src_base + (size_t)(mb * 32 + row0) * K_DIM + ktg * 256) + col4;
        #pragma unroll
        for (int p = 0; p < 8; p++) {
            int row = p * 4 + row0;
            tile[row * 64 + (col4 ^ (row & 7))] = src[(size_t)p * 4 * (K_DIM / 4)];
        }
    }
    __syncthreads();

    // ---- encode: warp w -> kt_local; lane gathers 32 consecutive floats from LDS ----
    int w = t >> 6;                   // kt_local 0..3
    int l = t & 63;
    int row = l & 31;
    int ub = w * 16 + (l >> 5) * 8;
    uint32_t o[4];
    #pragma unroll
    for (int d = 0; d < 4; d++) {
        float4 f0 = tile[row * 64 + ((ub + 2 * d)     ^ (row & 7))];
        float4 f1 = tile[row * 64 + ((ub + 2 * d + 1) ^ (row & 7))];
        o[d] =  enc_nib_t(f0.x, t0,t1,t2,t3,t4,t5,t6)
             | (enc_nib_t(f0.y, t0,t1,t2,t3,t4,t5,t6) << 4)
             | (enc_nib_t(f0.z, t0,t1,t2,t3,t4,t5,t6) << 8)
             | (enc_nib_t(f0.w, t0,t1,t2,t3,t4,t5,t6) << 12)
             | (enc_nib_t(f1.x, t0,t1,t2,t3,t4,t5,t6) << 16)
             | (enc_nib_t(f1.y, t0,t1,t2,t3,t4,t5,t6) << 20)
             | (enc_nib_t(f1.z, t0,t1,t2,t3,t4,t5,t6) << 24)
             | (enc_nib_t(f1.w, t0,t1,t2,t3,t4,t5,t6) << 28);
    }
    int kt = ktg * 4 + w;
    *(uint4*)(dst + ((size_t)(mb * 64 + kt) * 64 + l) * 4) = make_uint4(o[0], o[1], o[2], o[3]);
}

// ---------------- fp4 MX GEMM: C = (A·B^T)*scale + bias ----------------
// 256x256 tile, 8 waves (2Mx4N, wave=128x64), 4-deep LDS ring (64 KB).
// 2 K-tiles per iteration, counted lgkmcnt phase interleave:
//   {vmcnt(4); bar; 12 reads; frags0; 8 MFMA; lgkm(0); bar2; 4 glds; frags1; 8 MFMA}
#define NWG 512

__device__ __forceinline__ void glds16(const uint32_t* g, uint32_t* l) {
    __builtin_amdgcn_global_load_lds(AS1(g), AS3(l), 16, 0, 0);
}

__device__ __forceinline__ i32x8 dupfrag(uint4 u) {
    i32x8 v;
    v[0] = u.x; v[1] = u.y; v[2] = u.z; v[3] = u.w;   // fp4 uses 4 regs; duplicate to
    v[4] = u.x; v[5] = u.y; v[6] = u.z; v[7] = u.w;   // cover either half convention
    return v;
}

__global__ __launch_bounds__(512, 2)
void gemm_kernel(const uint32_t* __restrict__ Ap, const uint32_t* __restrict__ Bp,
                 const float* __restrict__ bias, float* __restrict__ C,
                 const double* __restrict__ sums) {
    __shared__ uint32_t lds[4 * 4096];   // 4 ring slots x (A 8KB + B 8KB)

    int bid = blockIdx.x;
    int swz = (bid & 7) * (NWG >> 3) + (bid >> 3);  // 512 % 8 == 0 -> bijective
    int bn = (swz & 15) * 256;
    int bm = (swz >> 4) * 256;

    int t = threadIdx.x;
    int lane = t & 63;
    int wm = (t >> 6) >> 2;          // 0..1
    int wn = (t >> 6) & 3;           // 0..3

    const uint32_t* gA = Ap + (size_t)((bm >> 5) + (t >> 6)) * 16384 + (t & 63) * 4;
    const uint32_t* gB = Bp + (size_t)((bn >> 5) + (t >> 6)) * 16384 + (t & 63) * 4;
    uint32_t* ldA = lds + t * 4;           // slot-local A region: [0, 2048) dwords
    uint32_t* ldB = lds + 2048 + t * 4;    // slot-local B region: [2048, 4096)

    int offA[4], offB[2];
    #pragma unroll
    for (int m = 0; m < 4; m++) offA[m] = ((wm * 4 + m) * 64 + lane) * 4;
    #pragma unroll
    for (int n = 0; n < 2; n++) offB[n] = 2048 + ((wn * 2 + n) * 64 + lane) * 4;

    f32x16 acc[8][2];   // [tile-pair m slots: 0-3 even kt handled via same acc] -> acc[m][n], m over 4 per phase
    #pragma unroll
    for (int m = 0; m < 8; m++)
        #pragma unroll
        for (int n = 0; n < 2; n++) acc[m][n] = (f32x16)0.f;
    // NOTE: acc[0..3][n] accumulate phase-0 (even+odd tiles both add into same acc via m index)
    // Actually: acc[m][n] m=0..3 used by BOTH clusters (same output block). Use 4x2 only:
    // (kept 8x2 declaration collapsed below — see clusters; unused half optimized out)

    // prologue: stage K-tiles 0..3
    #pragma unroll
    for (int pt = 0; pt < 4; pt++) {
        glds16(gA + pt * 256, ldA + pt * 4096);
        glds16(gB + pt * 256, ldB + pt * 4096);
    }

    for (int s = 0; s < 32; s++) {
        if (s < 31) asm volatile("s_waitcnt vmcnt(4)" ::: "memory");
        else        asm volatile("s_waitcnt vmcnt(0)" ::: "memory");
        asm volatile("s_barrier" ::: "memory");

        const uint32_t* rb0 = lds + (s & 1) * 8192;   // slot 2(s&1):   tile 2s
        const uint32_t* rb1 = rb0 + 4096;             // slot 2(s&1)+1: tile 2s+1

        // ---- issue all 12 reads (tile0 first: in-order DS returns) ----
        uint4 A0[4], B0[2], A1[4], B1[2];
        #pragma unroll
        for (int m = 0; m < 4; m++) A0[m] = *(const uint4*)&rb0[offA[m]];
        #pragma unroll
        for (int n = 0; n < 2; n++) B0[n] = *(const uint4*)&rb0[offB[n]];
        #pragma unroll
        for (int m = 0; m < 4; m++) A1[m] = *(const uint4*)&rb1[offA[m]];
        #pragma unroll
        for (int n = 0; n < 2; n++) B1[n] = *(const uint4*)&rb1[offB[n]];

        // ---- cluster 0: waits only tile-0 reads (counted lgkmcnt), tile-1 in flight ----
        {
            i32x8 va0 = dupfrag(A0[0]), va1 = dupfrag(A0[1]), va2 = dupfrag(A0[2]), va3 = dupfrag(A0[3]);
            i32x8 vb0 = dupfrag(B0[0]), vb1 = dupfrag(B0[1]);
            __builtin_amdgcn_s_setprio(1);
            acc[0][0] = __builtin_amdgcn_mfma_scale_f32_32x32x64_f8f6f4(va0, vb0, acc[0][0], 4, 4, 0, 0x7F7F7F7F, 0, 0x7F7F7F7F);
            acc[0][1] = __builtin_amdgcn_mfma_scale_f32_32x32x64_f8f6f4(va0, vb1, acc[0][1], 4, 4, 0, 0x7F7F7F7F, 0, 0x7F7F7F7F);
            acc[1][0] = __builtin_amdgcn_mfma_scale_f32_32x32x64_f8f6f4(va1, vb0, acc[1][0], 4, 4, 0, 0x7F7F7F7F, 0, 0x7F7F7F7F);
            acc[1][1] = __builtin_amdgcn_mfma_scale_f32_32x32x64_f8f6f4(va1, vb1, acc[1][1], 4, 4, 0, 0x7F7F7F7F, 0, 0x7F7F7F7F);
            acc[2][0] = __builtin_amdgcn_mfma_scale_f32_32x32x64_f8f6f4(va2, vb0, acc[2][0], 4, 4, 0, 0x7F7F7F7F, 0, 0x7F7F7F7F);
            acc[2][1] = __builtin_amdgcn_mfma_scale_f32_32x32x64_f8f6f4(va2, vb1, acc[2][1], 4, 4, 0, 0x7F7F7F7F, 0, 0x7F7F7F7F);
            acc[3][0] = __builtin_amdgcn_mfma_scale_f32_32x32x64_f8f6f4(va3, vb0, acc[3][0], 4, 4, 0, 0x7F7F7F7F, 0, 0x7F7F7F7F);
            acc[3][1] = __builtin_amdgcn_mfma_scale_f32_32x32x64_f8f6f4(va3, vb1, acc[3][1], 4, 4, 0, 0x7F7F7F7F, 0, 0x7F7F7F7F);
            __builtin_amdgcn_s_setprio(0);
        }

        // ---- all reads done (cross-wave WAR fence), then reuse slots for prefetch ----
        asm volatile("s_waitcnt lgkmcnt(0)" ::: "memory");
        __builtin_amdgcn_sched_barrier(0);
        asm volatile("s_barrier" ::: "memory");
        if (s < 30) {
            int so = (s & 1) * 8192;
            glds16(gA + (2 * s + 4) * 256, ldA + so);
            glds16(gB + (2 * s + 4) * 256, ldB + so);
            glds16(gA + (2 * s + 5) * 256, ldA + so + 4096);
            glds16(gB + (2 * s + 5) * 256, ldB + so + 4096);
        }

        // ---- cluster 1: tile 2s+1 (regs already loaded) ----
        {
            i32x8 va0 = dupfrag(A1[0]), va1 = dupfrag(A1[1]), va2 = dupfrag(A1[2]), va3 = dupfrag(A1[3]);
            i32x8 vb0 = dupfrag(B1[0]), vb1 = dupfrag(B1[1]);
            __builtin_amdgcn_s_setprio(1);
            acc[0][0] = __builtin_amdgcn_mfma_scale_f32_32x32x64_f8f6f4(va0, vb0, acc[0][0], 4, 4, 0, 0x7F7F7F7F, 0, 0x7F7F7F7F);
            acc[0][1] = __builtin_amdgcn_mfma_scale_f32_32x32x64_f8f6f4(va0, vb1, acc[0][1], 4, 4, 0, 0x7F7F7F7F, 0, 0x7F7F7F7F);
            acc[1][0] = __builtin_amdgcn_mfma_scale_f32_32x32x64_f8f6f4(va1, vb0, acc[1][0], 4, 4, 0, 0x7F7F7F7F, 0, 0x7F7F7F7F);
            acc[1][1] = __builtin_amdgcn_mfma_scale_f32_32x32x64_f8f6f4(va1, vb1, acc[1][1], 4, 4, 0, 0x7F7F7F7F, 0, 0x7F7F7F7F);
            acc[2][0] = __builtin_amdgcn_mfma_scale_f32_32x32x64_f8f6f4(va2, vb0, acc[2][0], 4, 4, 0, 0x7F7F7F7F, 0, 0x7F7F7F7F);
            acc[2][1] = __builtin_amdgcn_mfma_scale_f32_32x32x64_f8f6f4(va2, vb1, acc[2][1], 4, 4, 0, 0x7F7F7F7F, 0, 0x7F7F7F7F);
            acc[3][0] = __builtin_amdgcn_mfma_scale_f32_32x32x64_f8f6f4(va3, vb0, acc[3][0], 4, 4, 0, 0x7F7F7F7F, 0, 0x7F7F7F7F);
            acc[3][1] = __builtin_amdgcn_mfma_scale_f32_32x32x64_f8f6f4(va3, vb1, acc[3][1], 4, 4, 0, 0x7F7F7F7F, 0, 0x7F7F7F7F);
            __builtin_amdgcn_s_setprio(0);
        }
    }

    float scale = (float)((sums[0] * (1.0 / 33554432.0)) * (sums[1] * (1.0 / 16777216.0)));

    // C/D 32x32 layout: col=lane&31, row=(i&3)+8*(i>>2)+4*(lane>>5)
    int colb = bn + wn * 64 + (lane & 31);
    int rowb = bm + wm * 128 + ((lane >> 5) << 2);
    #pragma unroll
    for (int m = 0; m < 4; m++)
        #pragma unroll
        for (int n = 0; n < 2; n++) {
            int col = colb + n * 32;
            float bv = bias[col];
            #pragma unroll
            for (int i = 0; i < 16; i++) {
                int row = rowb + m * 32 + (i & 3) + ((i >> 2) << 3);
                C[(size_t)row * N_DIM + col] = acc[m][n][i] * scale + bv;
            }
        }
}

extern "C" void kernel_launch(void* const* d_in, const int* in_sizes, int n_in,
                              void* d_out, int out_size, void* d_ws, size_t ws_size,
                              hipStream_t stream) {
    const float* x    = (const float*)d_in[0];   // [4,2048,4096]
    const float* w    = (const float*)d_in[1];   // [4096,4096]
    const float* bias = (const float*)d_in[2];   // [4096]
    float* out = (float*)d_out;                  // [4,2048,4096] fp32

    double* sums = (double*)d_ws;
    uint32_t* Xp = (uint32_t*)((char*)d_ws + 1024);   // 16 MB packed fp4, fragment-major
    uint32_t* Wp = Xp + (size_t)256 * 64 * 64 * 4;    // 8 MB

    hipMemsetAsync(d_ws, 0, 1024, stream);
    absum2_kernel<<<3072, 256, 0, stream>>>(x, w, sums);
    quant2_kernel<<<6144, 256, 0, stream>>>(x, w, Xp, Wp, sums);
    gemm_kernel<<<NWG, 512, 0, stream>>>(Xp, Wp, bias, out, sums);
}